// Round 9
// baseline (976.391 us; speedup 1.0000x reference)
//
#include <hip/hip_runtime.h>
#include <stdint.h>

// Vector quantizer, bit-exact emulation of the numpy-f32 reference pipeline:
//   Sx[n] = np.sum(x_flat*x_flat, 1)   (numpy pairwise_sum, n=256)
//   M     = x_flat @ cb.T              (BLAS: sequential FMA over c ascending)
//   dist  = fl(fl(Sx - 2M) + Se),  idx = argmin (first min)
// x (16,256,1500) f32, codebook (2048,256) f32.
// out = [quantized (B,C,T) | indices (B,1,T) as float | loss] f32.
//
// Round 9 structure: round 4's tile (64 rows x 256 codes, 8x8 micro-tile)
// with the x operand moved OFF the LDS pipe. Round 4's 65.4% VALUBusy ==
// the LDS issue ceiling (128 ds_read_b128/c-step x ~12cyc = 1536 > 1024 VALU
// share -> 67%). Now: cb from LDS (64 reads), x via global_load_dwordx4 with
// immediate offsets (L1/L2-hot, 2 base regs, zero addr VALU) -> LDS util 75%,
// VALU-bound. LDS 32KB -> 4 blocks/CU; grid 3072 = 12/CU, 3 even rotations.

#define B_DIM 16
#define C_DIM 256
#define T_DIM 1500
#define K_CODES 2048
#define N_ROWS (B_DIM * T_DIM)               // 24000
#define TOTAL_ELEMS (B_DIM * C_DIM * T_DIM)  // 6144000

#define TM 64        // t-rows per argmin block
#define TKC 256      // codes per block (== k-slice)
#define CS 32        // c per step
#define OT 64        // t per output block

__device__ __forceinline__ void gl_lds16(const float* g, float* l) {
    __builtin_amdgcn_global_load_lds(
        (const __attribute__((address_space(1))) void*)(uintptr_t)g,
        (__attribute__((address_space(3))) void*)(uintptr_t)l, 16, 0, 0);
}

// ---------------- kernel T: x (B,C,T) -> xT (B,T,C) in d_out scratch --------
__global__ __launch_bounds__(256) void vq_transpose(const float* __restrict__ x,
                                                    float* __restrict__ xT) {
    __shared__ float tile[32][33];
    const int b = blockIdx.z;
    const int t0 = blockIdx.x * 32;
    const int c0 = blockIdx.y * 32;
    const int tx = threadIdx.x & 31;
    const int ty = threadIdx.x >> 5;          // 0..7
#pragma unroll
    for (int q = 0; q < 4; ++q) {
        const int c = c0 + ty * 4 + q;
        int t = t0 + tx; if (t >= T_DIM) t = T_DIM - 1;
        tile[ty * 4 + q][tx] = x[((size_t)b * C_DIM + c) * T_DIM + t];
    }
    __syncthreads();
#pragma unroll
    for (int q = 0; q < 4; ++q) {
        const int t = t0 + ty * 4 + q;
        if (t < T_DIM)
            xT[((size_t)b * T_DIM + t) * C_DIM + c0 + tx] = tile[tx][ty * 4 + q];
    }
}

// ---------------- kernel A: Se[k] = np-pairwise sum of cb row squares -------
__global__ __launch_bounds__(256) void vq_se(const float* __restrict__ cb,
                                             float* __restrict__ Se) {
    const int k = blockIdx.x * 256 + threadIdx.x;
    if (k >= K_CODES) return;
    const float* row = cb + (size_t)k * C_DIM;
    float h[2];
#pragma unroll
    for (int half = 0; half < 2; ++half) {
        const float* a = row + half * 128;
        float r[8];
#pragma unroll
        for (int j = 0; j < 8; ++j) r[j] = __fmul_rn(a[j], a[j]);
        for (int i = 8; i < 128; i += 8)
#pragma unroll
            for (int j = 0; j < 8; ++j)
                r[j] = __fadd_rn(r[j], __fmul_rn(a[i + j], a[i + j]));
        h[half] = __fadd_rn(
            __fadd_rn(__fadd_rn(r[0], r[1]), __fadd_rn(r[2], r[3])),
            __fadd_rn(__fadd_rn(r[4], r[5]), __fadd_rn(r[6], r[7])));
    }
    Se[k] = __fadd_rn(h[0], h[1]);
}

// ---------------- kernel B: Sx[n] from xT rows (same pairwise order) --------
__global__ __launch_bounds__(256) void vq_sx(const float* __restrict__ xT,
                                             float* __restrict__ Sx) {
    const int n = blockIdx.x * 256 + threadIdx.x;
    if (n >= N_ROWS) return;
    const float* row = xT + (size_t)n * C_DIM;
    float h[2];
#pragma unroll
    for (int half = 0; half < 2; ++half) {
        const float* a = row + half * 128;
        float r[8];
#pragma unroll
        for (int j = 0; j < 8; ++j) r[j] = __fmul_rn(a[j], a[j]);
        for (int i = 8; i < 128; i += 8)
#pragma unroll
            for (int j = 0; j < 8; ++j)
                r[j] = __fadd_rn(r[j], __fmul_rn(a[i + j], a[i + j]));
        h[half] = __fadd_rn(
            __fadd_rn(__fadd_rn(r[0], r[1]), __fadd_rn(r[2], r[3])),
            __fadd_rn(__fadd_rn(r[4], r[5]), __fadd_rn(r[6], r[7])));
    }
    Sx[n] = __fadd_rn(h[0], h[1]);
}

// ---------------- kernel I: init u64 argmin slots ---------------------------
__global__ void vq_init(unsigned long long* __restrict__ slots) {
    const int n = blockIdx.x * 256 + threadIdx.x;
    if (n < N_ROWS) slots[n] = ~0ull;
}

// ---------------- kernel C: fused GEMM + argmin (bit-exact np-f32) ----------
// grid (24 t-tiles, 16 b, 8 k-slices), 256 threads.
// thread (tr=tid&7, tcol=tid>>3): micro-tile 8 rows x 8 codes.
// cb: global_load_lds staged, XOR-swizzled, conflict-free ds_read_b128.
// x: direct global_load_dwordx4 (2 base ptrs + imm offsets), L1/L2-hot.
__global__ __launch_bounds__(256, 4) void vq_argmin(
    const float* __restrict__ xT, const float* __restrict__ cb,
    const float* __restrict__ Se, const float* __restrict__ Sx,
    unsigned long long* __restrict__ slots) {
    __shared__ float cs[TKC * CS];       // 32 KB (merge phase aliases it)

    const int tid = threadIdx.x;
    const int t0 = blockIdx.x * TM;
    const int b = blockIdx.y;
    const int k0 = blockIdx.z * TKC;
    const int tr = tid & 7;
    const int tcol = tid >> 3;           // 0..31

    // x bases: rows t0+tr*8 .. +7 (NO clamp; overflow reads stay inside d_out
    // and are discarded at merge). i 0..3 from xb0, 4..7 from xb4 (imm offs).
    const float* xb0 = xT + ((size_t)b * T_DIM + t0 + tr * 8) * C_DIM;
    const float* xb4 = xb0 + 4 * C_DIM;

    float acc[8][8];
#pragma unroll
    for (int i = 0; i < 8; ++i)
#pragma unroll
        for (int j = 0; j < 8; ++j) acc[i][j] = 0.f;

#pragma unroll 1
    for (int c0 = 0; c0 < C_DIM; c0 += CS) {
        __syncthreads();                 // prev compute done reading cs
        // ---- stage CB tile: 256 codes x 32 c, pre-swizzled source
#pragma unroll
        for (int i = 0; i < 8; ++i) {
            const int A = i * 256 + tid;
            const int kk = A >> 3, slot = A & 7;
            const int g4 = slot ^ ((kk >> 3) & 7);
            gl_lds16(cb + (size_t)(k0 + kk) * C_DIM + c0 + g4 * 4, &cs[A * 4]);
        }
        __syncthreads();                 // cs ready (vmcnt drained here)
        // ---- compute: c ascending (granule g, then .x.y.z.w)
#pragma unroll
        for (int g = 0; g < 8; ++g) {
            float4 cv[8];
#pragma unroll
            for (int j = 0; j < 8; ++j)
                cv[j] = *reinterpret_cast<const float4*>(
                    &cs[(tcol * 8 + j) * CS + ((g ^ (tcol & 7)) << 2)]);
#pragma unroll
            for (int ih = 0; ih < 2; ++ih) {
                const float* xb = ih ? xb4 : xb0;
#pragma unroll
                for (int ii = 0; ii < 4; ++ii) {
                    const int i = ih * 4 + ii;
                    const float4 xv = *reinterpret_cast<const float4*>(
                        xb + (size_t)ii * C_DIM + c0 + g * 4);
#pragma unroll
                    for (int j = 0; j < 8; ++j) {
                        acc[i][j] = fmaf(xv.x, cv[j].x, acc[i][j]);
                        acc[i][j] = fmaf(xv.y, cv[j].y, acc[i][j]);
                        acc[i][j] = fmaf(xv.z, cv[j].z, acc[i][j]);
                        acc[i][j] = fmaf(xv.w, cv[j].w, acc[i][j]);
                    }
                }
            }
        }
    }

    // ---- score: dist = fl(fl(Sx - 2*M) + Se); first-min (k ascending)
    float sxr[8], evr[8];
#pragma unroll
    for (int i = 0; i < 8; ++i) {
        int t = t0 + tr * 8 + i; if (t >= T_DIM) t = T_DIM - 1;
        sxr[i] = Sx[b * T_DIM + t];
    }
    {
        const float4 e0 = *reinterpret_cast<const float4*>(Se + k0 + tcol * 8);
        const float4 e1 = *reinterpret_cast<const float4*>(Se + k0 + tcol * 8 + 4);
        evr[0] = e0.x; evr[1] = e0.y; evr[2] = e0.z; evr[3] = e0.w;
        evr[4] = e1.x; evr[5] = e1.y; evr[6] = e1.z; evr[7] = e1.w;
    }
    float m1[8];
    int k1[8];
#pragma unroll
    for (int i = 0; i < 8; ++i) { m1[i] = 1e30f; k1[i] = 0x7fffffff; }
#pragma unroll
    for (int j = 0; j < 8; ++j) {
        const int kg = k0 + tcol * 8 + j;
#pragma unroll
        for (int i = 0; i < 8; ++i) {
            const float s = __fadd_rn(
                __fsub_rn(sxr[i], __fmul_rn(2.0f, acc[i][j])), evr[j]);
            if (s < m1[i]) { m1[i] = s; k1[i] = kg; }
        }
    }

    // ---- cross-thread merge (32 threads per row), transposed, alias cs
    __syncthreads();
    float* redm = cs;                          // [32][64]
    int* redk = reinterpret_cast<int*>(cs + 32 * 64);
#pragma unroll
    for (int i = 0; i < 8; ++i) {
        const int r = tr * 8 + i;
        redm[tcol * 64 + r] = m1[i];
        redk[tcol * 64 + r] = k1[i];
    }
    __syncthreads();
    if (tid < TM) {
        const int r = tid;
        float bm = 1e30f;
        int bk = 0x7fffffff;
        for (int tc = 0; tc < 32; ++tc) {
            const float c1 = redm[tc * 64 + r];
            const int ck = redk[tc * 64 + r];
            if (c1 < bm || (c1 == bm && ck < bk)) { bm = c1; bk = ck; }
        }
        const int t = t0 + r;
        if (t < T_DIM) {
            const unsigned long long pack =
                ((unsigned long long)__float_as_uint(bm) << 32) | (unsigned)bk;
            atomicMin(slots + b * T_DIM + t, pack);
        }
    }
}

// ---------------- kernel D: gather + STE output + indices + loss partials ---
__global__ __launch_bounds__(256) void vq_output(
    const float* __restrict__ x, const float* __restrict__ cb,
    const unsigned long long* __restrict__ slots, float* __restrict__ out,
    float* __restrict__ partials) {
    const int tid = threadIdx.x;
    const int b = blockIdx.y;
    const int t0 = blockIdx.x * OT;
    __shared__ int idxs[OT];
    if (tid < OT) {
        const int t = t0 + tid;
        if (t < T_DIM) {
            const int id = (int)(unsigned)(slots[b * T_DIM + t] & 0xffffffffull);
            idxs[tid] = id;
            out[(size_t)TOTAL_ELEMS + b * T_DIM + t] = (float)id;   // indices
        }
    }
    __syncthreads();
    const int ti = tid & 63;
    const int cq = tid >> 6;       // 0..3
    const int t = t0 + ti;
    float lsum = 0.f;
    if (t < T_DIM) {
        const int id = idxs[ti];
        for (int c0 = 0; c0 < C_DIM; c0 += 4) {
            const int c = c0 + cq;
            const size_t off = (size_t)(b * C_DIM + c) * T_DIM + t;
            const float xv = x[off];
            const float q = cb[(size_t)id * C_DIM + c];
            out[off] = __fadd_rn(xv, __fsub_rn(q, xv));   // STE, np-exact
            const float d = __fsub_rn(q, xv);
            lsum = fmaf(d, d, lsum);
        }
    }
#pragma unroll
    for (int off = 32; off; off >>= 1) lsum += __shfl_down(lsum, off, 64);
    __shared__ float wsum[4];
    if ((tid & 63) == 0) wsum[tid >> 6] = lsum;
    __syncthreads();
    if (tid == 0)
        partials[blockIdx.y * gridDim.x + blockIdx.x] =
            wsum[0] + wsum[1] + wsum[2] + wsum[3];
}

// ---------------- kernel E: final loss reduce -------------------------------
__global__ void vq_loss(const float* __restrict__ partials, int nparts,
                        float* __restrict__ out) {
    __shared__ float red[256];
    float s = 0.f;
    for (int i = threadIdx.x; i < nparts; i += 256) s += partials[i];
    red[threadIdx.x] = s;
    __syncthreads();
    for (int off = 128; off; off >>= 1) {
        if (threadIdx.x < off) red[threadIdx.x] += red[threadIdx.x + off];
        __syncthreads();
    }
    if (threadIdx.x == 0)
        out[(size_t)TOTAL_ELEMS + N_ROWS] = red[0] * (1.0f / (float)TOTAL_ELEMS);
}

// ---------------- launch -----------------------------------------------------
extern "C" void kernel_launch(void* const* d_in, const int* in_sizes, int n_in,
                              void* d_out, int out_size, void* d_ws, size_t ws_size,
                              hipStream_t stream) {
    const float* x = (const float*)d_in[0];
    const float* cb = (const float*)d_in[1];
    float* out = (float*)d_out;

    // xT scratch lives in d_out[0 .. 6144000) (overwritten by vq_output later)
    float* xT = out;

    // ws layout (bytes): Se 8K | Sx 96000 | slots (u64, 8-aligned) | partials
    float* Se = (float*)d_ws;
    float* Sx = Se + K_CODES;
    unsigned long long* slots =
        (unsigned long long*)((char*)d_ws + ((8192 + 96000 + 7) & ~7ull));
    float* partials = (float*)(slots + N_ROWS);

    vq_transpose<<<dim3(47, 8, B_DIM), dim3(256), 0, stream>>>(x, xT);
    vq_se<<<dim3(K_CODES / 256), dim3(256), 0, stream>>>(cb, Se);
    vq_sx<<<dim3((N_ROWS + 255) / 256), dim3(256), 0, stream>>>(xT, Sx);
    vq_init<<<dim3((N_ROWS + 255) / 256), dim3(256), 0, stream>>>(slots);
    vq_argmin<<<dim3((T_DIM + TM - 1) / TM, B_DIM, K_CODES / TKC),
                dim3(256), 0, stream>>>(xT, cb, Se, Sx, slots);
    vq_output<<<dim3((T_DIM + OT - 1) / OT, B_DIM), dim3(256), 0, stream>>>(
        x, cb, slots, out, partials);
    vq_loss<<<dim3(1), dim3(256), 0, stream>>>(
        partials, (T_DIM + OT - 1) / OT * B_DIM, out);
}

// Round 10
// 849.641 us; speedup vs baseline: 1.1492x; 1.1492x over previous
//
#include <hip/hip_runtime.h>
#include <stdint.h>

// Vector quantizer, bit-exact emulation of the numpy-f32 reference pipeline:
//   Sx[n] = np.sum(x_flat*x_flat, 1)   (numpy pairwise_sum, n=256)
//   M     = x_flat @ cb.T              (BLAS: sequential FMA over c ascending)
//   dist  = fl(fl(Sx - 2M) + Se),  idx = argmin (first min)
// x (16,256,1500) f32, codebook (2048,256) f32.
// out = [quantized (B,C,T) | indices (B,1,T) as float | loss] f32.
//
// Round 10: round 9's structure (cb staged via global_load_lds + XOR-swizzled
// ds_read_b128; x per-lane global_load_dwordx4 with imm offsets) with the
// REGISTER BUDGET FIXED. Empirical toolchain law (r5/r9): with 256-thread
// blocks, __launch_bounds__(256, w) caps VGPRs at 256/w -> w=2 gives 128,
// enough for acc[64]+xv[32]+addressing (~120). r9's (256,4) forced 64 regs
// and spilled 775 MB to scratch. Inner loop: per granule g, 8 VMEM xv loads,
// then per code j one cv ds_read feeding 8 FMA chains (8 LDS reads/g).

#define B_DIM 16
#define C_DIM 256
#define T_DIM 1500
#define K_CODES 2048
#define N_ROWS (B_DIM * T_DIM)               // 24000
#define TOTAL_ELEMS (B_DIM * C_DIM * T_DIM)  // 6144000

#define TM 64        // t-rows per argmin block
#define TKC 256      // codes per block (== k-slice)
#define CS 32        // c per step
#define OT 64        // t per output block

__device__ __forceinline__ void gl_lds16(const float* g, float* l) {
    __builtin_amdgcn_global_load_lds(
        (const __attribute__((address_space(1))) void*)(uintptr_t)g,
        (__attribute__((address_space(3))) void*)(uintptr_t)l, 16, 0, 0);
}

// ---------------- kernel T: x (B,C,T) -> xT (B,T,C) in d_out scratch --------
__global__ __launch_bounds__(256) void vq_transpose(const float* __restrict__ x,
                                                    float* __restrict__ xT) {
    __shared__ float tile[32][33];
    const int b = blockIdx.z;
    const int t0 = blockIdx.x * 32;
    const int c0 = blockIdx.y * 32;
    const int tx = threadIdx.x & 31;
    const int ty = threadIdx.x >> 5;          // 0..7
#pragma unroll
    for (int q = 0; q < 4; ++q) {
        const int c = c0 + ty * 4 + q;
        int t = t0 + tx; if (t >= T_DIM) t = T_DIM - 1;
        tile[ty * 4 + q][tx] = x[((size_t)b * C_DIM + c) * T_DIM + t];
    }
    __syncthreads();
#pragma unroll
    for (int q = 0; q < 4; ++q) {
        const int t = t0 + ty * 4 + q;
        if (t < T_DIM)
            xT[((size_t)b * T_DIM + t) * C_DIM + c0 + tx] = tile[tx][ty * 4 + q];
    }
}

// ---------------- kernel A: Se[k] = np-pairwise sum of cb row squares -------
__global__ __launch_bounds__(256) void vq_se(const float* __restrict__ cb,
                                             float* __restrict__ Se) {
    const int k = blockIdx.x * 256 + threadIdx.x;
    if (k >= K_CODES) return;
    const float* row = cb + (size_t)k * C_DIM;
    float h[2];
#pragma unroll
    for (int half = 0; half < 2; ++half) {
        const float* a = row + half * 128;
        float r[8];
#pragma unroll
        for (int j = 0; j < 8; ++j) r[j] = __fmul_rn(a[j], a[j]);
        for (int i = 8; i < 128; i += 8)
#pragma unroll
            for (int j = 0; j < 8; ++j)
                r[j] = __fadd_rn(r[j], __fmul_rn(a[i + j], a[i + j]));
        h[half] = __fadd_rn(
            __fadd_rn(__fadd_rn(r[0], r[1]), __fadd_rn(r[2], r[3])),
            __fadd_rn(__fadd_rn(r[4], r[5]), __fadd_rn(r[6], r[7])));
    }
    Se[k] = __fadd_rn(h[0], h[1]);
}

// ---------------- kernel B: Sx[n] from xT rows (same pairwise order) --------
__global__ __launch_bounds__(256) void vq_sx(const float* __restrict__ xT,
                                             float* __restrict__ Sx) {
    const int n = blockIdx.x * 256 + threadIdx.x;
    if (n >= N_ROWS) return;
    const float* row = xT + (size_t)n * C_DIM;
    float h[2];
#pragma unroll
    for (int half = 0; half < 2; ++half) {
        const float* a = row + half * 128;
        float r[8];
#pragma unroll
        for (int j = 0; j < 8; ++j) r[j] = __fmul_rn(a[j], a[j]);
        for (int i = 8; i < 128; i += 8)
#pragma unroll
            for (int j = 0; j < 8; ++j)
                r[j] = __fadd_rn(r[j], __fmul_rn(a[i + j], a[i + j]));
        h[half] = __fadd_rn(
            __fadd_rn(__fadd_rn(r[0], r[1]), __fadd_rn(r[2], r[3])),
            __fadd_rn(__fadd_rn(r[4], r[5]), __fadd_rn(r[6], r[7])));
    }
    Sx[n] = __fadd_rn(h[0], h[1]);
}

// ---------------- kernel I: init u64 argmin slots ---------------------------
__global__ void vq_init(unsigned long long* __restrict__ slots) {
    const int n = blockIdx.x * 256 + threadIdx.x;
    if (n < N_ROWS) slots[n] = ~0ull;
}

// ---------------- kernel C: fused GEMM + argmin (bit-exact np-f32) ----------
// grid (24 t-tiles, 16 b, 8 k-slices), 256 threads.
// thread (tr=tid&7, tcol=tid>>3): micro-tile 8 rows x 8 codes.
// cb: global_load_lds staged, XOR-swizzled, conflict-free ds_read_b128.
// x: direct global_load_dwordx4 (2 base ptrs + imm offsets), L1/L2-hot.
__global__ __launch_bounds__(256, 2) void vq_argmin(
    const float* __restrict__ xT, const float* __restrict__ cb,
    const float* __restrict__ Se, const float* __restrict__ Sx,
    unsigned long long* __restrict__ slots) {
    __shared__ float cs[TKC * CS];       // 32 KB (merge phase aliases it)

    const int tid = threadIdx.x;
    const int t0 = blockIdx.x * TM;
    const int b = blockIdx.y;
    const int k0 = blockIdx.z * TKC;
    const int tr = tid & 7;
    const int tcol = tid >> 3;           // 0..31

    // x bases: rows t0+tr*8 .. +7 (NO clamp; overflow reads stay inside d_out
    // and are discarded at merge). i 0..3 from xb0, 4..7 from xb4 (imm offs).
    const float* xb0 = xT + ((size_t)b * T_DIM + t0 + tr * 8) * C_DIM;
    const float* xb4 = xb0 + 4 * C_DIM;

    float acc[8][8];
#pragma unroll
    for (int i = 0; i < 8; ++i)
#pragma unroll
        for (int j = 0; j < 8; ++j) acc[i][j] = 0.f;

#pragma unroll 1
    for (int c0 = 0; c0 < C_DIM; c0 += CS) {
        __syncthreads();                 // prev compute done reading cs
        // ---- stage CB tile: 256 codes x 32 c, pre-swizzled source
#pragma unroll
        for (int i = 0; i < 8; ++i) {
            const int A = i * 256 + tid;
            const int kk = A >> 3, slot = A & 7;
            const int g4 = slot ^ ((kk >> 3) & 7);
            gl_lds16(cb + (size_t)(k0 + kk) * C_DIM + c0 + g4 * 4, &cs[A * 4]);
        }
        __syncthreads();                 // cs ready (vmcnt drained here)
        // ---- compute: c ascending (granule g, then .x.y.z.w)
#pragma unroll
        for (int g = 0; g < 8; ++g) {
            float4 xv[8];
#pragma unroll
            for (int ii = 0; ii < 4; ++ii) {
                xv[ii] = *reinterpret_cast<const float4*>(
                    xb0 + (size_t)ii * C_DIM + c0 + g * 4);
                xv[4 + ii] = *reinterpret_cast<const float4*>(
                    xb4 + (size_t)ii * C_DIM + c0 + g * 4);
            }
#pragma unroll
            for (int j = 0; j < 8; ++j) {
                const float4 cv = *reinterpret_cast<const float4*>(
                    &cs[(tcol * 8 + j) * CS + ((g ^ (tcol & 7)) << 2)]);
#pragma unroll
                for (int i = 0; i < 8; ++i) {
                    acc[i][j] = fmaf(xv[i].x, cv.x, acc[i][j]);
                    acc[i][j] = fmaf(xv[i].y, cv.y, acc[i][j]);
                    acc[i][j] = fmaf(xv[i].z, cv.z, acc[i][j]);
                    acc[i][j] = fmaf(xv[i].w, cv.w, acc[i][j]);
                }
            }
        }
    }

    // ---- score: dist = fl(fl(Sx - 2*M) + Se); first-min (k ascending)
    float sxr[8], evr[8];
#pragma unroll
    for (int i = 0; i < 8; ++i) {
        int t = t0 + tr * 8 + i; if (t >= T_DIM) t = T_DIM - 1;
        sxr[i] = Sx[b * T_DIM + t];
    }
    {
        const float4 e0 = *reinterpret_cast<const float4*>(Se + k0 + tcol * 8);
        const float4 e1 = *reinterpret_cast<const float4*>(Se + k0 + tcol * 8 + 4);
        evr[0] = e0.x; evr[1] = e0.y; evr[2] = e0.z; evr[3] = e0.w;
        evr[4] = e1.x; evr[5] = e1.y; evr[6] = e1.z; evr[7] = e1.w;
    }
    float m1[8];
    int k1[8];
#pragma unroll
    for (int i = 0; i < 8; ++i) { m1[i] = 1e30f; k1[i] = 0x7fffffff; }
#pragma unroll
    for (int j = 0; j < 8; ++j) {
        const int kg = k0 + tcol * 8 + j;
#pragma unroll
        for (int i = 0; i < 8; ++i) {
            const float s = __fadd_rn(
                __fsub_rn(sxr[i], __fmul_rn(2.0f, acc[i][j])), evr[j]);
            if (s < m1[i]) { m1[i] = s; k1[i] = kg; }
        }
    }

    // ---- cross-thread merge (32 threads per row), transposed, alias cs
    __syncthreads();
    float* redm = cs;                          // [32][64]
    int* redk = reinterpret_cast<int*>(cs + 32 * 64);
#pragma unroll
    for (int i = 0; i < 8; ++i) {
        const int r = tr * 8 + i;
        redm[tcol * 64 + r] = m1[i];
        redk[tcol * 64 + r] = k1[i];
    }
    __syncthreads();
    if (tid < TM) {
        const int r = tid;
        float bm = 1e30f;
        int bk = 0x7fffffff;
        for (int tc = 0; tc < 32; ++tc) {
            const float c1 = redm[tc * 64 + r];
            const int ck = redk[tc * 64 + r];
            if (c1 < bm || (c1 == bm && ck < bk)) { bm = c1; bk = ck; }
        }
        const int t = t0 + r;
        if (t < T_DIM) {
            const unsigned long long pack =
                ((unsigned long long)__float_as_uint(bm) << 32) | (unsigned)bk;
            atomicMin(slots + b * T_DIM + t, pack);
        }
    }
}

// ---------------- kernel D: gather + STE output + indices + loss partials ---
__global__ __launch_bounds__(256) void vq_output(
    const float* __restrict__ x, const float* __restrict__ cb,
    const unsigned long long* __restrict__ slots, float* __restrict__ out,
    float* __restrict__ partials) {
    const int tid = threadIdx.x;
    const int b = blockIdx.y;
    const int t0 = blockIdx.x * OT;
    __shared__ int idxs[OT];
    if (tid < OT) {
        const int t = t0 + tid;
        if (t < T_DIM) {
            const int id = (int)(unsigned)(slots[b * T_DIM + t] & 0xffffffffull);
            idxs[tid] = id;
            out[(size_t)TOTAL_ELEMS + b * T_DIM + t] = (float)id;   // indices
        }
    }
    __syncthreads();
    const int ti = tid & 63;
    const int cq = tid >> 6;       // 0..3
    const int t = t0 + ti;
    float lsum = 0.f;
    if (t < T_DIM) {
        const int id = idxs[ti];
        for (int c0 = 0; c0 < C_DIM; c0 += 4) {
            const int c = c0 + cq;
            const size_t off = (size_t)(b * C_DIM + c) * T_DIM + t;
            const float xv = x[off];
            const float q = cb[(size_t)id * C_DIM + c];
            out[off] = __fadd_rn(xv, __fsub_rn(q, xv));   // STE, np-exact
            const float d = __fsub_rn(q, xv);
            lsum = fmaf(d, d, lsum);
        }
    }
#pragma unroll
    for (int off = 32; off; off >>= 1) lsum += __shfl_down(lsum, off, 64);
    __shared__ float wsum[4];
    if ((tid & 63) == 0) wsum[tid >> 6] = lsum;
    __syncthreads();
    if (tid == 0)
        partials[blockIdx.y * gridDim.x + blockIdx.x] =
            wsum[0] + wsum[1] + wsum[2] + wsum[3];
}

// ---------------- kernel E: final loss reduce -------------------------------
__global__ void vq_loss(const float* __restrict__ partials, int nparts,
                        float* __restrict__ out) {
    __shared__ float red[256];
    float s = 0.f;
    for (int i = threadIdx.x; i < nparts; i += 256) s += partials[i];
    red[threadIdx.x] = s;
    __syncthreads();
    for (int off = 128; off; off >>= 1) {
        if (threadIdx.x < off) red[threadIdx.x] += red[threadIdx.x + off];
        __syncthreads();
    }
    if (threadIdx.x == 0)
        out[(size_t)TOTAL_ELEMS + N_ROWS] = red[0] * (1.0f / (float)TOTAL_ELEMS);
}

// ---------------- launch -----------------------------------------------------
extern "C" void kernel_launch(void* const* d_in, const int* in_sizes, int n_in,
                              void* d_out, int out_size, void* d_ws, size_t ws_size,
                              hipStream_t stream) {
    const float* x = (const float*)d_in[0];
    const float* cb = (const float*)d_in[1];
    float* out = (float*)d_out;

    // xT scratch lives in d_out[0 .. 6144000) (overwritten by vq_output later)
    float* xT = out;

    // ws layout (bytes): Se 8K | Sx 96000 | slots (u64, 8-aligned) | partials
    float* Se = (float*)d_ws;
    float* Sx = Se + K_CODES;
    unsigned long long* slots =
        (unsigned long long*)((char*)d_ws + ((8192 + 96000 + 7) & ~7ull));
    float* partials = (float*)(slots + N_ROWS);

    vq_transpose<<<dim3(47, 8, B_DIM), dim3(256), 0, stream>>>(x, xT);
    vq_se<<<dim3(K_CODES / 256), dim3(256), 0, stream>>>(cb, Se);
    vq_sx<<<dim3((N_ROWS + 255) / 256), dim3(256), 0, stream>>>(xT, Sx);
    vq_init<<<dim3((N_ROWS + 255) / 256), dim3(256), 0, stream>>>(slots);
    vq_argmin<<<dim3((T_DIM + TM - 1) / TM, B_DIM, K_CODES / TKC),
                dim3(256), 0, stream>>>(xT, cb, Se, Sx, slots);
    vq_output<<<dim3((T_DIM + OT - 1) / OT, B_DIM), dim3(256), 0, stream>>>(
        x, cb, slots, out, partials);
    vq_loss<<<dim3(1), dim3(256), 0, stream>>>(
        partials, (T_DIM + OT - 1) / OT * B_DIM, out);
}

// Round 11
// 489.769 us; speedup vs baseline: 1.9936x; 1.7348x over previous
//
#include <hip/hip_runtime.h>
#include <stdint.h>

// Vector quantizer, bit-exact emulation of the numpy-f32 reference pipeline:
//   Sx[n] = np.sum(x_flat*x_flat, 1)   (numpy pairwise_sum, n=256)
//   M     = x_flat @ cb.T              (BLAS: sequential FMA over c ascending)
//   dist  = fl(fl(Sx - 2M) + Se),  idx = argmin (first min)
// x (16,256,1500) f32, codebook (2048,256) f32.
// out = [quantized (B,C,T) | indices (B,1,T) as float | loss] f32.
//
// Round 11: r4's LDS-both-operands tile (64 rows x 256 codes, 8x8 micro-tile,
// 65.4% VALU = the 67% LDS-issue ceiling: 128 ds_read_b128/c-step x 12cyc =
// 6144 CU-cyc vs 4096 VALU-cyc) with overhead removed:
//  - X staged via global_load_lds from xT (was: scalar scatter + VALU)
//  - double-buffered, ONE barrier per c-step (STAGE next; COMPUTE cur; sync)
//  - no __launch_bounds__ reg cap (r5/r9 spill lesson), straight-line buffers
// LDS floor model: ~246 us for vq_argmin; target total ~300 us.

#define B_DIM 16
#define C_DIM 256
#define T_DIM 1500
#define K_CODES 2048
#define N_ROWS (B_DIM * T_DIM)               // 24000
#define TOTAL_ELEMS (B_DIM * C_DIM * T_DIM)  // 6144000

#define TM 64        // t-rows per argmin block
#define TKC 256      // codes per chunk
#define KSLICE 512   // codes per block (2 chunks)
#define CS 32        // c per step
#define OT 64        // t per output block

__device__ __forceinline__ void gl_lds16(const float* g, float* l) {
    __builtin_amdgcn_global_load_lds(
        (const __attribute__((address_space(1))) void*)(uintptr_t)g,
        (__attribute__((address_space(3))) void*)(uintptr_t)l, 16, 0, 0);
}

// ---------------- kernel T: x (B,C,T) -> xT (B,T,C) in d_out scratch --------
__global__ __launch_bounds__(256) void vq_transpose(const float* __restrict__ x,
                                                    float* __restrict__ xT) {
    __shared__ float tile[32][33];
    const int b = blockIdx.z;
    const int t0 = blockIdx.x * 32;
    const int c0 = blockIdx.y * 32;
    const int tx = threadIdx.x & 31;
    const int ty = threadIdx.x >> 5;          // 0..7
#pragma unroll
    for (int q = 0; q < 4; ++q) {
        const int c = c0 + ty * 4 + q;
        int t = t0 + tx; if (t >= T_DIM) t = T_DIM - 1;
        tile[ty * 4 + q][tx] = x[((size_t)b * C_DIM + c) * T_DIM + t];
    }
    __syncthreads();
#pragma unroll
    for (int q = 0; q < 4; ++q) {
        const int t = t0 + ty * 4 + q;
        if (t < T_DIM)
            xT[((size_t)b * T_DIM + t) * C_DIM + c0 + tx] = tile[tx][ty * 4 + q];
    }
}

// ---------------- kernel A: Se[k] = np-pairwise sum of cb row squares -------
__global__ __launch_bounds__(256) void vq_se(const float* __restrict__ cb,
                                             float* __restrict__ Se) {
    const int k = blockIdx.x * 256 + threadIdx.x;
    if (k >= K_CODES) return;
    const float* row = cb + (size_t)k * C_DIM;
    float h[2];
#pragma unroll
    for (int half = 0; half < 2; ++half) {
        const float* a = row + half * 128;
        float r[8];
#pragma unroll
        for (int j = 0; j < 8; ++j) r[j] = __fmul_rn(a[j], a[j]);
        for (int i = 8; i < 128; i += 8)
#pragma unroll
            for (int j = 0; j < 8; ++j)
                r[j] = __fadd_rn(r[j], __fmul_rn(a[i + j], a[i + j]));
        h[half] = __fadd_rn(
            __fadd_rn(__fadd_rn(r[0], r[1]), __fadd_rn(r[2], r[3])),
            __fadd_rn(__fadd_rn(r[4], r[5]), __fadd_rn(r[6], r[7])));
    }
    Se[k] = __fadd_rn(h[0], h[1]);
}

// ---------------- kernel B: Sx[n] from xT rows (same pairwise order) --------
__global__ __launch_bounds__(256) void vq_sx(const float* __restrict__ xT,
                                             float* __restrict__ Sx) {
    const int n = blockIdx.x * 256 + threadIdx.x;
    if (n >= N_ROWS) return;
    const float* row = xT + (size_t)n * C_DIM;
    float h[2];
#pragma unroll
    for (int half = 0; half < 2; ++half) {
        const float* a = row + half * 128;
        float r[8];
#pragma unroll
        for (int j = 0; j < 8; ++j) r[j] = __fmul_rn(a[j], a[j]);
        for (int i = 8; i < 128; i += 8)
#pragma unroll
            for (int j = 0; j < 8; ++j)
                r[j] = __fadd_rn(r[j], __fmul_rn(a[i + j], a[i + j]));
        h[half] = __fadd_rn(
            __fadd_rn(__fadd_rn(r[0], r[1]), __fadd_rn(r[2], r[3])),
            __fadd_rn(__fadd_rn(r[4], r[5]), __fadd_rn(r[6], r[7])));
    }
    Sx[n] = __fadd_rn(h[0], h[1]);
}

// ---------------- kernel I: init u64 argmin slots ---------------------------
__global__ void vq_init(unsigned long long* __restrict__ slots) {
    const int n = blockIdx.x * 256 + threadIdx.x;
    if (n < N_ROWS) slots[n] = ~0ull;
}

// ---- staging: X (64x32) = 2 gl_lds, CB (256x32) = 8 gl_lds per thread.
// LDS slot s of row r holds granule g = s ^ ((r>>3)&7)  (self-inverting XOR;
// linear gl_lds dest, pre-swizzled global source).
#define STAGE(XS, CSB, K0_, C0_) do {                                          \
    _Pragma("unroll")                                                          \
    for (int p_ = 0; p_ < 2; ++p_) {                                           \
        const int A_ = p_ * 256 + tid;                                         \
        const int r_ = A_ >> 3, s_ = A_ & 7;                                   \
        const int g_ = s_ ^ ((r_ >> 3) & 7);                                   \
        gl_lds16(xTb + (size_t)(t0 + r_) * C_DIM + (C0_) + g_ * 4,             \
                 &XS[A_ * 4]);                                                 \
    }                                                                          \
    _Pragma("unroll")                                                          \
    for (int i_ = 0; i_ < 8; ++i_) {                                           \
        const int A_ = i_ * 256 + tid;                                         \
        const int kk_ = A_ >> 3, s_ = A_ & 7;                                  \
        const int g_ = s_ ^ ((kk_ >> 3) & 7);                                  \
        gl_lds16(cb + (size_t)((K0_) + kk_) * C_DIM + (C0_) + g_ * 4,          \
                 &CSB[A_ * 4]);                                                \
    } } while (0)

// ---- compute one c-step: c ascending (granule g, then .x.y.z.w); per g:
// 8 xv ds_read (key g^tr) + 8 cv ds_read (key g^(tcol&7)) + 256 FMA.
#define COMPUTE(XS, CSB) do {                                                  \
    _Pragma("unroll")                                                          \
    for (int g_ = 0; g_ < 8; ++g_) {                                           \
        float4 xv[8];                                                          \
        _Pragma("unroll")                                                      \
        for (int i_ = 0; i_ < 8; ++i_)                                         \
            xv[i_] = *reinterpret_cast<const float4*>(                         \
                &XS[(tr * 8 + i_) * CS + ((g_ ^ tr) << 2)]);                   \
        _Pragma("unroll")                                                      \
        for (int j_ = 0; j_ < 8; ++j_) {                                       \
            const float4 cv = *reinterpret_cast<const float4*>(                \
                &CSB[(tcol * 8 + j_) * CS + ((g_ ^ (tcol & 7)) << 2)]);        \
            _Pragma("unroll")                                                  \
            for (int i_ = 0; i_ < 8; ++i_) {                                   \
                acc[i_][j_] = fmaf(xv[i_].x, cv.x, acc[i_][j_]);               \
                acc[i_][j_] = fmaf(xv[i_].y, cv.y, acc[i_][j_]);               \
                acc[i_][j_] = fmaf(xv[i_].z, cv.z, acc[i_][j_]);               \
                acc[i_][j_] = fmaf(xv[i_].w, cv.w, acc[i_][j_]);               \
            } } } } while (0)

// ---------------- kernel C: fused GEMM + argmin (bit-exact np-f32) ----------
// grid (24 t-tiles, 16 b, 4 k-slices), 256 threads, dbuf single-barrier loop.
__global__ __launch_bounds__(256) void vq_argmin(
    const float* __restrict__ xT, const float* __restrict__ cb,
    const float* __restrict__ Se, const float* __restrict__ Sx,
    unsigned long long* __restrict__ slots) {
    __shared__ float xs0[TM * CS], xs1[TM * CS];     // 8 KB each
    __shared__ float cs0[TKC * CS], cs1[TKC * CS];   // 32 KB each

    const int tid = threadIdx.x;
    const int t0 = blockIdx.x * TM;
    const int b = blockIdx.y;
    const int k0b = blockIdx.z * KSLICE;
    const int tr = tid & 7;
    const int tcol = tid >> 3;           // 0..31

    const float* xTb = xT + (size_t)b * T_DIM * C_DIM;

    float sxr[8];
#pragma unroll
    for (int i = 0; i < 8; ++i) {
        int t = t0 + tr * 8 + i; if (t >= T_DIM) t = T_DIM - 1;
        sxr[i] = Sx[b * T_DIM + t];
    }

    float m1[8];
    int k1[8];
    float acc[8][8];
#pragma unroll
    for (int i = 0; i < 8; ++i) {
        m1[i] = 1e30f; k1[i] = 0x7fffffff;
#pragma unroll
        for (int j = 0; j < 8; ++j) acc[i][j] = 0.f;
    }

#pragma unroll 1
    for (int kc = 0; kc < KSLICE / TKC; ++kc) {
        const int k0 = k0b + kc * TKC;
        STAGE(xs0, cs0, k0, 0);
        __syncthreads();
#pragma unroll 1
        for (int cp = 0; cp < 3; ++cp) {
            const int c0 = cp * 64;
            STAGE(xs1, cs1, k0, c0 + 32);
            COMPUTE(xs0, cs0);
            __syncthreads();
            STAGE(xs0, cs0, k0, c0 + 64);
            COMPUTE(xs1, cs1);
            __syncthreads();
        }
        STAGE(xs1, cs1, k0, 224);
        COMPUTE(xs0, cs0);               // c = 192
        __syncthreads();
        COMPUTE(xs1, cs1);               // c = 224
        // ---- score: dist = fl(fl(Sx - 2*M) + Se); first-min (k ascending)
        float evr[8];
        {
            const float4 e0 = *reinterpret_cast<const float4*>(Se + k0 + tcol * 8);
            const float4 e1 = *reinterpret_cast<const float4*>(Se + k0 + tcol * 8 + 4);
            evr[0] = e0.x; evr[1] = e0.y; evr[2] = e0.z; evr[3] = e0.w;
            evr[4] = e1.x; evr[5] = e1.y; evr[6] = e1.z; evr[7] = e1.w;
        }
#pragma unroll
        for (int j = 0; j < 8; ++j) {
            const int kg = k0 + tcol * 8 + j;
#pragma unroll
            for (int i = 0; i < 8; ++i) {
                const float s = __fadd_rn(
                    __fsub_rn(sxr[i], __fmul_rn(2.0f, acc[i][j])), evr[j]);
                if (s < m1[i]) { m1[i] = s; k1[i] = kg; }
                acc[i][j] = 0.f;
            }
        }
        // next chunk's STAGE(xs0/cs0) is safe: last reader of those buffers
        // (c=192 COMPUTE) is behind a barrier; c=224 readers use xs1/cs1.
    }

    // ---- cross-thread merge (32 threads per row), transposed, alias cs0
    float* redm = cs0;                         // [32][64]
    int* redk = reinterpret_cast<int*>(cs0 + 32 * 64);
#pragma unroll
    for (int i = 0; i < 8; ++i) {
        const int r = tr * 8 + i;
        redm[tcol * 64 + r] = m1[i];
        redk[tcol * 64 + r] = k1[i];
    }
    __syncthreads();
    if (tid < TM) {
        const int r = tid;
        float bm = 1e30f;
        int bk = 0x7fffffff;
        for (int tc = 0; tc < 32; ++tc) {
            const float c1 = redm[tc * 64 + r];
            const int ck = redk[tc * 64 + r];
            if (c1 < bm || (c1 == bm && ck < bk)) { bm = c1; bk = ck; }
        }
        const int t = t0 + r;
        if (t < T_DIM) {
            const unsigned long long pack =
                ((unsigned long long)__float_as_uint(bm) << 32) | (unsigned)bk;
            atomicMin(slots + b * T_DIM + t, pack);
        }
    }
}

// ---------------- kernel D: gather + STE output + indices + loss partials ---
__global__ __launch_bounds__(256) void vq_output(
    const float* __restrict__ x, const float* __restrict__ cb,
    const unsigned long long* __restrict__ slots, float* __restrict__ out,
    float* __restrict__ partials) {
    const int tid = threadIdx.x;
    const int b = blockIdx.y;
    const int t0 = blockIdx.x * OT;
    __shared__ int idxs[OT];
    if (tid < OT) {
        const int t = t0 + tid;
        if (t < T_DIM) {
            const int id = (int)(unsigned)(slots[b * T_DIM + t] & 0xffffffffull);
            idxs[tid] = id;
            out[(size_t)TOTAL_ELEMS + b * T_DIM + t] = (float)id;   // indices
        }
    }
    __syncthreads();
    const int ti = tid & 63;
    const int cq = tid >> 6;       // 0..3
    const int t = t0 + ti;
    float lsum = 0.f;
    if (t < T_DIM) {
        const int id = idxs[ti];
        for (int c0 = 0; c0 < C_DIM; c0 += 4) {
            const int c = c0 + cq;
            const size_t off = (size_t)(b * C_DIM + c) * T_DIM + t;
            const float xv = x[off];
            const float q = cb[(size_t)id * C_DIM + c];
            out[off] = __fadd_rn(xv, __fsub_rn(q, xv));   // STE, np-exact
            const float d = __fsub_rn(q, xv);
            lsum = fmaf(d, d, lsum);
        }
    }
#pragma unroll
    for (int off = 32; off; off >>= 1) lsum += __shfl_down(lsum, off, 64);
    __shared__ float wsum[4];
    if ((tid & 63) == 0) wsum[tid >> 6] = lsum;
    __syncthreads();
    if (tid == 0)
        partials[blockIdx.y * gridDim.x + blockIdx.x] =
            wsum[0] + wsum[1] + wsum[2] + wsum[3];
}

// ---------------- kernel E: final loss reduce -------------------------------
__global__ void vq_loss(const float* __restrict__ partials, int nparts,
                        float* __restrict__ out) {
    __shared__ float red[256];
    float s = 0.f;
    for (int i = threadIdx.x; i < nparts; i += 256) s += partials[i];
    red[threadIdx.x] = s;
    __syncthreads();
    for (int off = 128; off; off >>= 1) {
        if (threadIdx.x < off) red[threadIdx.x] += red[threadIdx.x + off];
        __syncthreads();
    }
    if (threadIdx.x == 0)
        out[(size_t)TOTAL_ELEMS + N_ROWS] = red[0] * (1.0f / (float)TOTAL_ELEMS);
}

// ---------------- launch -----------------------------------------------------
extern "C" void kernel_launch(void* const* d_in, const int* in_sizes, int n_in,
                              void* d_out, int out_size, void* d_ws, size_t ws_size,
                              hipStream_t stream) {
    const float* x = (const float*)d_in[0];
    const float* cb = (const float*)d_in[1];
    float* out = (float*)d_out;

    // xT scratch lives in d_out[0 .. 6144000) (overwritten by vq_output later)
    float* xT = out;

    // ws layout (bytes): Se 8K | Sx 96000 | slots (u64, 8-aligned) | partials
    float* Se = (float*)d_ws;
    float* Sx = Se + K_CODES;
    unsigned long long* slots =
        (unsigned long long*)((char*)d_ws + ((8192 + 96000 + 7) & ~7ull));
    float* partials = (float*)(slots + N_ROWS);

    vq_transpose<<<dim3(47, 8, B_DIM), dim3(256), 0, stream>>>(x, xT);
    vq_se<<<dim3(K_CODES / 256), dim3(256), 0, stream>>>(cb, Se);
    vq_sx<<<dim3((N_ROWS + 255) / 256), dim3(256), 0, stream>>>(xT, Sx);
    vq_init<<<dim3((N_ROWS + 255) / 256), dim3(256), 0, stream>>>(slots);
    vq_argmin<<<dim3((T_DIM + TM - 1) / TM, B_DIM, K_CODES / KSLICE),
                dim3(256), 0, stream>>>(xT, cb, Se, Sx, slots);
    vq_output<<<dim3((T_DIM + OT - 1) / OT, B_DIM), dim3(256), 0, stream>>>(
        x, cb, slots, out, partials);
    vq_loss<<<dim3(1), dim3(256), 0, stream>>>(
        partials, (T_DIM + OT - 1) / OT * B_DIM, out);
}

// Round 12
// 428.354 us; speedup vs baseline: 2.2794x; 1.1434x over previous
//
#include <hip/hip_runtime.h>
#include <stdint.h>

// Vector quantizer, bit-exact emulation of the numpy-f32 reference pipeline:
//   Sx[n] = np.sum(x_flat*x_flat, 1)   (numpy pairwise_sum, n=256)
//   M     = x_flat @ cb.T              (BLAS: sequential FMA over c ascending)
//   dist  = fl(fl(Sx - 2M) + Se),  idx = argmin (first min)
// x (16,256,1500) f32, codebook (2048,256) f32.
// out = [quantized (B,C,T) | indices (B,1,T) as float | loss] f32.
//
// Round 12: break the LDS data-path ceiling via BROADCAST x reads.
// Wave <-> 16 shared rows (xv reads wave-uniform -> ~free on the LDS data
// path), lane <-> 2 codes (only cv reads move full 1024 B/instr). LDS data
// demand per block-c-step: 512KB (r4) -> ~68KB = 0.44x of VALU demand.
// LDS 24KB, ~70 live VGPRs -> high residency hides stage drains.
// Argmin merge: per-row 6-step __shfl_xor u64 min (no LDS), 1 atomic/row.

#define B_DIM 16
#define C_DIM 256
#define T_DIM 1500
#define K_CODES 2048
#define N_ROWS (B_DIM * T_DIM)               // 24000
#define TOTAL_ELEMS (B_DIM * C_DIM * T_DIM)  // 6144000

#define RPW 16       // rows per wave (wave-shared)
#define TM 64        // rows per block (4 waves)
#define TKC 128      // codes per block (lane*2+j)
#define CS 32        // c per step
#define OT 64        // t per output block

__device__ __forceinline__ void gl_lds16(const float* g, float* l) {
    __builtin_amdgcn_global_load_lds(
        (const __attribute__((address_space(1))) void*)(uintptr_t)g,
        (__attribute__((address_space(3))) void*)(uintptr_t)l, 16, 0, 0);
}

// ---------------- kernel T: x (B,C,T) -> xT (B,T,C) in d_out scratch --------
__global__ __launch_bounds__(256) void vq_transpose(const float* __restrict__ x,
                                                    float* __restrict__ xT) {
    __shared__ float tile[32][33];
    const int b = blockIdx.z;
    const int t0 = blockIdx.x * 32;
    const int c0 = blockIdx.y * 32;
    const int tx = threadIdx.x & 31;
    const int ty = threadIdx.x >> 5;          // 0..7
#pragma unroll
    for (int q = 0; q < 4; ++q) {
        const int c = c0 + ty * 4 + q;
        int t = t0 + tx; if (t >= T_DIM) t = T_DIM - 1;
        tile[ty * 4 + q][tx] = x[((size_t)b * C_DIM + c) * T_DIM + t];
    }
    __syncthreads();
#pragma unroll
    for (int q = 0; q < 4; ++q) {
        const int t = t0 + ty * 4 + q;
        if (t < T_DIM)
            xT[((size_t)b * T_DIM + t) * C_DIM + c0 + tx] = tile[tx][ty * 4 + q];
    }
}

// ---------------- kernel A: Se[k] = np-pairwise sum of cb row squares -------
__global__ __launch_bounds__(256) void vq_se(const float* __restrict__ cb,
                                             float* __restrict__ Se) {
    const int k = blockIdx.x * 256 + threadIdx.x;
    if (k >= K_CODES) return;
    const float* row = cb + (size_t)k * C_DIM;
    float h[2];
#pragma unroll
    for (int half = 0; half < 2; ++half) {
        const float* a = row + half * 128;
        float r[8];
#pragma unroll
        for (int j = 0; j < 8; ++j) r[j] = __fmul_rn(a[j], a[j]);
        for (int i = 8; i < 128; i += 8)
#pragma unroll
            for (int j = 0; j < 8; ++j)
                r[j] = __fadd_rn(r[j], __fmul_rn(a[i + j], a[i + j]));
        h[half] = __fadd_rn(
            __fadd_rn(__fadd_rn(r[0], r[1]), __fadd_rn(r[2], r[3])),
            __fadd_rn(__fadd_rn(r[4], r[5]), __fadd_rn(r[6], r[7])));
    }
    Se[k] = __fadd_rn(h[0], h[1]);
}

// ---------------- kernel B: Sx[n] from xT rows (same pairwise order) --------
__global__ __launch_bounds__(256) void vq_sx(const float* __restrict__ xT,
                                             float* __restrict__ Sx) {
    const int n = blockIdx.x * 256 + threadIdx.x;
    if (n >= N_ROWS) return;
    const float* row = xT + (size_t)n * C_DIM;
    float h[2];
#pragma unroll
    for (int half = 0; half < 2; ++half) {
        const float* a = row + half * 128;
        float r[8];
#pragma unroll
        for (int j = 0; j < 8; ++j) r[j] = __fmul_rn(a[j], a[j]);
        for (int i = 8; i < 128; i += 8)
#pragma unroll
            for (int j = 0; j < 8; ++j)
                r[j] = __fadd_rn(r[j], __fmul_rn(a[i + j], a[i + j]));
        h[half] = __fadd_rn(
            __fadd_rn(__fadd_rn(r[0], r[1]), __fadd_rn(r[2], r[3])),
            __fadd_rn(__fadd_rn(r[4], r[5]), __fadd_rn(r[6], r[7])));
    }
    Sx[n] = __fadd_rn(h[0], h[1]);
}

// ---------------- kernel I: init u64 argmin slots ---------------------------
__global__ void vq_init(unsigned long long* __restrict__ slots) {
    const int n = blockIdx.x * 256 + threadIdx.x;
    if (n < N_ROWS) slots[n] = ~0ull;
}

// ---------------- kernel C: fused GEMM + argmin (bit-exact np-f32) ----------
// grid (16 k-slices, 24 row-tiles, 16 b), 256 threads = 4 waves.
// Wave w owns rows t0+16w..+15 (shared across its lanes; xv = broadcast LDS
// reads). Lane owns codes k0+lane*2+{0,1} (cv = swizzled conflict-free reads).
__global__ __launch_bounds__(256) void vq_argmin(
    const float* __restrict__ xT, const float* __restrict__ cb,
    const float* __restrict__ Se, const float* __restrict__ Sx,
    unsigned long long* __restrict__ slots) {
    __shared__ float xs[TM * CS];        // 8 KB, linear (broadcast reads)
    __shared__ float csm[TKC * CS];      // 16 KB, XOR-swizzled

    const int tid = threadIdx.x;
    const int wid = tid >> 6;
    const int lane = tid & 63;
    const int k0 = blockIdx.x * TKC;
    const int t0 = blockIdx.y * TM;
    const int b = blockIdx.z;

    const float* xTb = xT + (size_t)b * T_DIM * C_DIM;
    const int key = (lane >> 2) & 7;     // cv swizzle key = ((lane*2+j)>>3)&7

    float acc0[RPW], acc1[RPW];
#pragma unroll
    for (int r = 0; r < RPW; ++r) { acc0[r] = 0.f; acc1[r] = 0.f; }

    const float* xw = xs + wid * RPW * CS;
    const float* cb0 = csm + (lane * 2 + 0) * CS;
    const float* cb1 = csm + (lane * 2 + 1) * CS;

#pragma unroll 1
    for (int cp = 0; cp < C_DIM / CS; ++cp) {
        const int c0 = cp * CS;
        __syncthreads();                 // prev step's readers done
        // ---- stage X tile: 64 rows x 32 c, linear (broadcast-read later)
#pragma unroll
        for (int p = 0; p < 2; ++p) {
            const int A = p * 256 + tid;
            const int r = A >> 3, s = A & 7;
            gl_lds16(xTb + (size_t)(t0 + r) * C_DIM + c0 + s * 4, &xs[A * 4]);
        }
        // ---- stage CB tile: 128 codes x 32 c, pre-swizzled source
#pragma unroll
        for (int p = 0; p < 4; ++p) {
            const int A = p * 256 + tid;
            const int kk = A >> 3, s = A & 7;
            const int g4 = s ^ ((kk >> 3) & 7);
            gl_lds16(cb + (size_t)(k0 + kk) * C_DIM + c0 + g4 * 4, &csm[A * 4]);
        }
        __syncthreads();                 // tiles ready (vmcnt drained)
        // ---- compute: c ascending (granule g, then .x.y.z.w)
#pragma unroll
        for (int g = 0; g < 8; ++g) {
            const int gs = (g ^ key) << 2;
            const float4 cv0 = *reinterpret_cast<const float4*>(cb0 + gs);
            const float4 cv1 = *reinterpret_cast<const float4*>(cb1 + gs);
#pragma unroll
            for (int r = 0; r < RPW; ++r) {
                const float4 xv = *reinterpret_cast<const float4*>(
                    xw + r * CS + (g << 2));          // wave-uniform addr
                acc0[r] = fmaf(xv.x, cv0.x, acc0[r]);
                acc0[r] = fmaf(xv.y, cv0.y, acc0[r]);
                acc0[r] = fmaf(xv.z, cv0.z, acc0[r]);
                acc0[r] = fmaf(xv.w, cv0.w, acc0[r]);
                acc1[r] = fmaf(xv.x, cv1.x, acc1[r]);
                acc1[r] = fmaf(xv.y, cv1.y, acc1[r]);
                acc1[r] = fmaf(xv.z, cv1.z, acc1[r]);
                acc1[r] = fmaf(xv.w, cv1.w, acc1[r]);
            }
        }
    }

    // ---- score + per-row wave reduction (u64 pack, shfl_xor min) ----------
    const float2 se2 = *reinterpret_cast<const float2*>(Se + k0 + lane * 2);
    unsigned long long mine = ~0ull;
#pragma unroll
    for (int r = 0; r < RPW; ++r) {
        int trow = t0 + wid * RPW + r; if (trow >= T_DIM) trow = T_DIM - 1;
        const float sx = Sx[b * T_DIM + trow];
        const float s0 = __fadd_rn(__fsub_rn(sx, __fmul_rn(2.f, acc0[r])), se2.x);
        const float s1 = __fadd_rn(__fsub_rn(sx, __fmul_rn(2.f, acc1[r])), se2.y);
        float m; int k;
        if (s1 < s0) { m = s1; k = k0 + lane * 2 + 1; }
        else         { m = s0; k = k0 + lane * 2; }
        unsigned long long p =
            ((unsigned long long)__float_as_uint(m) << 32) | (unsigned)k;
#pragma unroll
        for (int off = 32; off >= 1; off >>= 1) {
            const unsigned long long q = __shfl_xor(p, off, 64);
            if (q < p) p = q;            // lexicographic (dist, k) min
        }
        mine = (lane == r) ? p : mine;
    }
    if (lane < RPW) {
        const int t = t0 + wid * RPW + lane;
        if (t < T_DIM) atomicMin(slots + b * T_DIM + t, mine);
    }
}

// ---------------- kernel D: gather + STE output + indices + loss partials ---
__global__ __launch_bounds__(256) void vq_output(
    const float* __restrict__ x, const float* __restrict__ cb,
    const unsigned long long* __restrict__ slots, float* __restrict__ out,
    float* __restrict__ partials) {
    const int tid = threadIdx.x;
    const int b = blockIdx.y;
    const int t0 = blockIdx.x * OT;
    __shared__ int idxs[OT];
    if (tid < OT) {
        const int t = t0 + tid;
        if (t < T_DIM) {
            const int id = (int)(unsigned)(slots[b * T_DIM + t] & 0xffffffffull);
            idxs[tid] = id;
            out[(size_t)TOTAL_ELEMS + b * T_DIM + t] = (float)id;   // indices
        }
    }
    __syncthreads();
    const int ti = tid & 63;
    const int cq = tid >> 6;       // 0..3
    const int t = t0 + ti;
    float lsum = 0.f;
    if (t < T_DIM) {
        const int id = idxs[ti];
        for (int c0 = 0; c0 < C_DIM; c0 += 4) {
            const int c = c0 + cq;
            const size_t off = (size_t)(b * C_DIM + c) * T_DIM + t;
            const float xv = x[off];
            const float q = cb[(size_t)id * C_DIM + c];
            out[off] = __fadd_rn(xv, __fsub_rn(q, xv));   // STE, np-exact
            const float d = __fsub_rn(q, xv);
            lsum = fmaf(d, d, lsum);
        }
    }
#pragma unroll
    for (int off = 32; off; off >>= 1) lsum += __shfl_down(lsum, off, 64);
    __shared__ float wsum[4];
    if ((tid & 63) == 0) wsum[tid >> 6] = lsum;
    __syncthreads();
    if (tid == 0)
        partials[blockIdx.y * gridDim.x + blockIdx.x] =
            wsum[0] + wsum[1] + wsum[2] + wsum[3];
}

// ---------------- kernel E: final loss reduce -------------------------------
__global__ void vq_loss(const float* __restrict__ partials, int nparts,
                        float* __restrict__ out) {
    __shared__ float red[256];
    float s = 0.f;
    for (int i = threadIdx.x; i < nparts; i += 256) s += partials[i];
    red[threadIdx.x] = s;
    __syncthreads();
    for (int off = 128; off; off >>= 1) {
        if (threadIdx.x < off) red[threadIdx.x] += red[threadIdx.x + off];
        __syncthreads();
    }
    if (threadIdx.x == 0)
        out[(size_t)TOTAL_ELEMS + N_ROWS] = red[0] * (1.0f / (float)TOTAL_ELEMS);
}

// ---------------- launch -----------------------------------------------------
extern "C" void kernel_launch(void* const* d_in, const int* in_sizes, int n_in,
                              void* d_out, int out_size, void* d_ws, size_t ws_size,
                              hipStream_t stream) {
    const float* x = (const float*)d_in[0];
    const float* cb = (const float*)d_in[1];
    float* out = (float*)d_out;

    // xT scratch lives in d_out[0 .. 6144000) (overwritten by vq_output later)
    float* xT = out;

    // ws layout (bytes): Se 8K | Sx 96000 | slots (u64, 8-aligned) | partials
    float* Se = (float*)d_ws;
    float* Sx = Se + K_CODES;
    unsigned long long* slots =
        (unsigned long long*)((char*)d_ws + ((8192 + 96000 + 7) & ~7ull));
    float* partials = (float*)(slots + N_ROWS);

    vq_transpose<<<dim3(47, 8, B_DIM), dim3(256), 0, stream>>>(x, xT);
    vq_se<<<dim3(K_CODES / 256), dim3(256), 0, stream>>>(cb, Se);
    vq_sx<<<dim3((N_ROWS + 255) / 256), dim3(256), 0, stream>>>(xT, Sx);
    vq_init<<<dim3((N_ROWS + 255) / 256), dim3(256), 0, stream>>>(slots);
    vq_argmin<<<dim3(K_CODES / TKC, (T_DIM + TM - 1) / TM, B_DIM),
                dim3(256), 0, stream>>>(xT, cb, Se, Sx, slots);
    vq_output<<<dim3((T_DIM + OT - 1) / OT, B_DIM), dim3(256), 0, stream>>>(
        x, cb, slots, out, partials);
    vq_loss<<<dim3(1), dim3(256), 0, stream>>>(
        partials, (T_DIM + OT - 1) / OT * B_DIM, out);
}